// Round 2
// baseline (228.020 us; speedup 1.0000x reference)
//
#include <hip/hip_runtime.h>
#include <math.h>

// PLIF forward: x[B,T,C,H,W] fp32, tau[C] fp32 -> spikes[B,T,C,H,W] fp32
// Per-site sequential scan over T with leak sigma(tau[c]) and hard reset.
constexpr int Bn = 32, Tn = 8, Cn = 128, Hn = 32, Wn = 32;
constexpr int HWv  = Hn * Wn;        // 1024
constexpr int CHW  = Cn * HWv;       // 131072
constexpr int CHW4 = CHW / 4;        // 32768  (float4 units)
constexpr int NV4  = Bn * CHW4;      // 1048576 threads total

__global__ __launch_bounds__(256) void plif_fwd(const float* __restrict__ x,
                                                const float* __restrict__ tau,
                                                float* __restrict__ out) {
    int i4 = blockIdx.x * blockDim.x + threadIdx.x;   // index over [B, CHW/4]
    if (i4 >= NV4) return;
    int b    = i4 >> 15;             // / CHW4
    int chw4 = i4 & (CHW4 - 1);
    int c    = chw4 >> 8;            // (chw4*4) / HW  (HW=1024)

    // sigma(tau[c]); tau==0 -> exactly 0.5, so the mem-chain below is
    // bitwise-identical to numpy regardless of FMA contraction.
    float ts = 1.0f / (1.0f + expf(-tau[c]));

    const float4* xv = (const float4*)x;
    float4*       ov = (float4*)out;
    int base = b * Tn * CHW4 + chw4; // max index 8,388,607 < 2^31: int is safe

    // Issue all 8 t-loads up front (independent addresses -> full MLP).
    float4 v[Tn];
#pragma unroll
    for (int t = 0; t < Tn; ++t) v[t] = xv[base + t * CHW4];

    // Sequential membrane scan; forbid contraction so semantics = mul-then-add.
    float m0 = 0.f, m1 = 0.f, m2 = 0.f, m3 = 0.f;
#pragma unroll
    for (int t = 0; t < Tn; ++t) {
        m0 = __fadd_rn(__fmul_rn(m0, ts), v[t].x);
        m1 = __fadd_rn(__fmul_rn(m1, ts), v[t].y);
        m2 = __fadd_rn(__fmul_rn(m2, ts), v[t].z);
        m3 = __fadd_rn(__fmul_rn(m3, ts), v[t].w);
        float4 s;
        s.x = (__fadd_rn(m0, -1.0f) > 0.0f) ? 1.0f : 0.0f;
        s.y = (__fadd_rn(m1, -1.0f) > 0.0f) ? 1.0f : 0.0f;
        s.z = (__fadd_rn(m2, -1.0f) > 0.0f) ? 1.0f : 0.0f;
        s.w = (__fadd_rn(m3, -1.0f) > 0.0f) ? 1.0f : 0.0f;
        m0 = (s.x > 0.f) ? 0.f : m0;   // hard reset
        m1 = (s.y > 0.f) ? 0.f : m1;
        m2 = (s.z > 0.f) ? 0.f : m2;
        m3 = (s.w > 0.f) ? 0.f : m3;
        ov[base + t * CHW4] = s;
    }
}

extern "C" void kernel_launch(void* const* d_in, const int* in_sizes, int n_in,
                              void* d_out, int out_size, void* d_ws, size_t ws_size,
                              hipStream_t stream) {
    const float* x   = (const float*)d_in[0];
    const float* tau = (const float*)d_in[1];
    float*       out = (float*)d_out;
    dim3 block(256);
    dim3 grid((NV4 + 255) / 256);   // 4096 blocks
    plif_fwd<<<grid, block, 0, stream>>>(x, tau, out);
}

// Round 4
// 219.926 us; speedup vs baseline: 1.0368x; 1.0368x over previous
//
#include <hip/hip_runtime.h>
#include <math.h>

// PLIF forward: x[B,T,C,H,W] fp32, tau[C] fp32 -> spikes[B,T,C,H,W] fp32
// Per-site sequential scan over T with leak sigma(tau[c]) and hard reset.
// Streaming kernel (zero reuse) -> nontemporal loads/stores.
// NOTE: __builtin_nontemporal_* requires a true clang vector type, not HIP's
// float4 struct -> use ext_vector_type(4).
typedef float fx4 __attribute__((ext_vector_type(4)));

constexpr int Bn = 32, Tn = 8, Cn = 128, Hn = 32, Wn = 32;
constexpr int HWv  = Hn * Wn;        // 1024
constexpr int CHW  = Cn * HWv;       // 131072
constexpr int CHW4 = CHW / 4;        // 32768  (fx4 units)
constexpr int NV4  = Bn * CHW4;      // 1048576 threads total

__global__ __launch_bounds__(256) void plif_fwd(const float* __restrict__ x,
                                                const float* __restrict__ tau,
                                                float* __restrict__ out) {
    int i4 = blockIdx.x * blockDim.x + threadIdx.x;   // index over [B, CHW/4]
    int b    = i4 >> 15;             // / CHW4
    int chw4 = i4 & (CHW4 - 1);
    int c    = chw4 >> 8;            // (chw4*4) / HW  (HW=1024)

    // sigma(tau[c]); tau==0 -> exactly 0.5, so the mem-chain below is
    // bitwise-identical to numpy regardless of FMA contraction.
    float ts = 1.0f / (1.0f + expf(-tau[c]));

    const fx4* xv = (const fx4*)x;
    fx4*       ov = (fx4*)out;
    int base = b * Tn * CHW4 + chw4; // max index 8,388,607 < 2^31: int is safe

    // Issue all 8 t-loads up front (independent addresses -> full MLP).
    // Nontemporal: this data is touched exactly once.
    fx4 v[Tn];
#pragma unroll
    for (int t = 0; t < Tn; ++t) v[t] = __builtin_nontemporal_load(&xv[base + t * CHW4]);

    // Sequential membrane scan; forbid contraction so semantics = mul-then-add.
    float m0 = 0.f, m1 = 0.f, m2 = 0.f, m3 = 0.f;
#pragma unroll
    for (int t = 0; t < Tn; ++t) {
        m0 = __fadd_rn(__fmul_rn(m0, ts), v[t].x);
        m1 = __fadd_rn(__fmul_rn(m1, ts), v[t].y);
        m2 = __fadd_rn(__fmul_rn(m2, ts), v[t].z);
        m3 = __fadd_rn(__fmul_rn(m3, ts), v[t].w);
        fx4 s;
        s.x = (__fadd_rn(m0, -1.0f) > 0.0f) ? 1.0f : 0.0f;
        s.y = (__fadd_rn(m1, -1.0f) > 0.0f) ? 1.0f : 0.0f;
        s.z = (__fadd_rn(m2, -1.0f) > 0.0f) ? 1.0f : 0.0f;
        s.w = (__fadd_rn(m3, -1.0f) > 0.0f) ? 1.0f : 0.0f;
        m0 = (s.x > 0.f) ? 0.f : m0;   // hard reset
        m1 = (s.y > 0.f) ? 0.f : m1;
        m2 = (s.z > 0.f) ? 0.f : m2;
        m3 = (s.w > 0.f) ? 0.f : m3;
        __builtin_nontemporal_store(s, &ov[base + t * CHW4]);
    }
}

extern "C" void kernel_launch(void* const* d_in, const int* in_sizes, int n_in,
                              void* d_out, int out_size, void* d_ws, size_t ws_size,
                              hipStream_t stream) {
    const float* x   = (const float*)d_in[0];
    const float* tau = (const float*)d_in[1];
    float*       out = (float*)d_out;
    dim3 block(256);
    dim3 grid(NV4 / 256);   // 4096 blocks, exact cover
    plif_fwd<<<grid, block, 0, stream>>>(x, tau, out);
}